// Round 21
// baseline (146.661 us; speedup 1.0000x reference)
//
#include <hip/hip_runtime.h>
#include <hip/hip_fp16.h>

#define HDIM 64
#define INDIM 128
#define OUTDIM 32
#define CAP 64        // padded-CSR capacity per node; deg ~ Poisson(16)
#define BNODES 128    // nodes per bucket (bucket = dst >> 7)
#define EPB 4096      // edges per block in pass A
#define BCAP 2304     // per-bucket edge capacity (mean 2046, +5.7 sigma)
#define SRCBITS 17    // src ids < 2^17 (n <= 131072)

typedef __attribute__((ext_vector_type(8))) _Float16 half8;
typedef __attribute__((ext_vector_type(16))) float f32x16;

__device__ __forceinline__ float2 h2f(unsigned int u) {
    return __half22float2(*(__half2*)&u);
}

// ---------------- K1: bin_edges (blocks < nbin) ∥ gemm_in (rest) -----------
// gemm_in emits UNSCALED h16a = fp16(x @ Win) — removing the rs pre-scale
// breaks the false dependency on build_csr, letting the input GEMM overlap
// the edge binning. Layer-0 aggregate applies rs[s] per edge instead.
__global__ __launch_bounds__(256) void bin_and_gemm_in(
    const int* __restrict__ dst, const int* __restrict__ srcp,
    int* __restrict__ gcur, int* __restrict__ binned, int e, int nb, int nbin,
    const float* __restrict__ x, const float* __restrict__ Win,
    __half* __restrict__ h16a, int n)
{
    __shared__ int hist[1024];
    __shared__ int base[1024];

    if ((int)blockIdx.x < nbin) {
        // ---------------- bin_edges body ----------------
        for (int i = threadIdx.x; i < nb; i += 256) hist[i] = 0;
        __syncthreads();

        int e0 = blockIdx.x * EPB + (int)threadIdx.x * 16;
        int d[16], s[16], p[16];
        bool vec_ok = ((e & 3) == 0);
        #pragma unroll
        for (int k = 0; k < 4; k++) {
            int i = e0 + 4 * k;
            if (vec_ok && i + 4 <= e) {
                int4 d4 = *(const int4*)(dst + i);
                int4 s4 = *(const int4*)(srcp + i);
                d[4*k+0] = d4.x; d[4*k+1] = d4.y; d[4*k+2] = d4.z; d[4*k+3] = d4.w;
                s[4*k+0] = s4.x; s[4*k+1] = s4.y; s[4*k+2] = s4.z; s[4*k+3] = s4.w;
            } else {
                #pragma unroll
                for (int j = 0; j < 4; j++) {
                    int ii = i + j;
                    if (ii < e) { d[4*k+j] = dst[ii]; s[4*k+j] = srcp[ii]; }
                    else        { d[4*k+j] = -1;      s[4*k+j] = 0; }
                }
            }
        }
        #pragma unroll
        for (int k = 0; k < 16; k++)
            if (d[k] >= 0) p[k] = atomicAdd(&hist[d[k] >> 7], 1);
        __syncthreads();
        for (int b = threadIdx.x; b < nb; b += 256) {
            int h = hist[b];
            base[b] = h ? atomicAdd(&gcur[b], h) : 0;
        }
        __syncthreads();
        #pragma unroll
        for (int k = 0; k < 16; k++) {
            if (d[k] < 0) continue;
            int b = d[k] >> 7;
            int pos = base[b] + p[k];
            if (pos < BCAP)
                binned[(size_t)b * BCAP + pos] =
                    ((d[k] & (BNODES - 1)) << SRCBITS) | s[k];
        }
    } else {
        // ---------------- gemm_in body (MFMA, K=128, no rs, no relu) -------
        constexpr int K = INDIM, KT = K / 16;
        int lane = (int)threadIdx.x & 63;
        int wave = (int)threadIdx.x >> 6;
        int col = lane & 31;
        int kq = lane >> 5;
        int gb = (int)blockIdx.x - nbin;
        int gcount = (int)gridDim.x - nbin;

        half8 bf[2][KT];
        #pragma unroll
        for (int nt = 0; nt < 2; nt++) {
            #pragma unroll
            for (int kt = 0; kt < KT; kt++) {
                int c = nt * 32 + col;
                int k0 = kt * 16 + kq * 8;
                half8 b;
                #pragma unroll
                for (int i = 0; i < 8; i++)
                    b[i] = (_Float16)Win[(size_t)(k0 + i) * HDIM + c];
                bf[nt][kt] = b;
            }
        }

        int ntiles = (n + 31) >> 5;
        for (int tile = gb * 4 + wave; tile < ntiles; tile += gcount * 4) {
            int rbase = tile * 32;
            int arow = rbase + col;
            arow = arow < n ? arow : n - 1;

            f32x16 acc0, acc1;
            #pragma unroll
            for (int i = 0; i < 16; i++) { acc0[i] = 0.f; acc1[i] = 0.f; }

            #pragma unroll
            for (int kt = 0; kt < KT; kt++) {
                int k0 = kt * 16 + kq * 8;
                const float* ap = x + (size_t)arow * K + k0;
                float4 x0 = *(const float4*)ap;
                float4 x1 = *(const float4*)(ap + 4);
                half8 af;
                af[0] = (_Float16)x0.x; af[1] = (_Float16)x0.y;
                af[2] = (_Float16)x0.z; af[3] = (_Float16)x0.w;
                af[4] = (_Float16)x1.x; af[5] = (_Float16)x1.y;
                af[6] = (_Float16)x1.z; af[7] = (_Float16)x1.w;
                acc0 = __builtin_amdgcn_mfma_f32_32x32x16_f16(af, bf[0][kt], acc0, 0, 0, 0);
                acc1 = __builtin_amdgcn_mfma_f32_32x32x16_f16(af, bf[1][kt], acc1, 0, 0, 0);
            }

            #pragma unroll
            for (int r = 0; r < 16; r++) {
                int row = rbase + (r & 3) + 8 * (r >> 2) + 4 * kq;
                if (row >= n) continue;
                h16a[(size_t)row * HDIM + col] = __float2half(acc0[r]);
                h16a[(size_t)row * HDIM + 32 + col] = __float2half(acc1[r]);
            }
        }
    }
}

// ---------------- pass B: per-bucket padded CSR built in LDS ----------------
__global__ __launch_bounds__(256) void build_csr(const int* __restrict__ gcur,
                                                 const int* __restrict__ binned,
                                                 int* __restrict__ cnt,
                                                 float* __restrict__ rs,
                                                 float* __restrict__ isr,
                                                 int* __restrict__ csr, int n) {
    __shared__ int lcsr[BNODES * CAP];   // 32 KiB
    __shared__ int lcnt[BNODES];
    if (threadIdx.x < BNODES) lcnt[threadIdx.x] = 0;
    __syncthreads();
    int b = blockIdx.x;
    int m = min(gcur[b], BCAP);
    const int* be = binned + (size_t)b * BCAP;
    for (int i = threadIdx.x; i < m; i += 256) {
        int v = be[i];
        int ld = v >> SRCBITS;
        int pos = atomicAdd(&lcnt[ld], 1);
        if (pos < CAP) lcsr[ld * CAP + pos] = v & ((1 << SRCBITS) - 1);
    }
    __syncthreads();
    int4* gout = (int4*)(csr + (size_t)b * (BNODES * CAP));
    const int4* lin = (const int4*)lcsr;
    #pragma unroll 2
    for (int i = threadIdx.x; i < BNODES * CAP / 4; i += 256) gout[i] = lin[i];
    int node = b * BNODES + (int)threadIdx.x;
    if (threadIdx.x < BNODES && node < n) {
        int c = lcnt[threadIdx.x];
        cnt[node] = c;
        float cf = (float)c + 1.0f;
        rs[node] = rsqrtf(cf);
        isr[node] = sqrtf(cf);
    }
}

// ---------------- MFMA mid GEMM: C16 = fp16(rs * relu(A16 @ W)) ------------
__global__ __launch_bounds__(256) void gemm_mid(const _Float16* __restrict__ A,
                                                const float* __restrict__ W,
                                                __half* __restrict__ C16,
                                                const float* __restrict__ rs,
                                                int n) {
    constexpr int K = HDIM, KT = K / 16;
    int lane = (int)threadIdx.x & 63;
    int wave = (int)threadIdx.x >> 6;
    int col = lane & 31;
    int kq = lane >> 5;

    half8 bf[2][KT];
    #pragma unroll
    for (int nt = 0; nt < 2; nt++) {
        #pragma unroll
        for (int kt = 0; kt < KT; kt++) {
            int c = nt * 32 + col;
            int k0 = kt * 16 + kq * 8;
            half8 b;
            #pragma unroll
            for (int i = 0; i < 8; i++)
                b[i] = (_Float16)W[(size_t)(k0 + i) * HDIM + c];
            bf[nt][kt] = b;
        }
    }

    int ntiles = (n + 31) >> 5;
    for (int tile = blockIdx.x * 4 + wave; tile < ntiles; tile += gridDim.x * 4) {
        int rbase = tile * 32;
        int arow = rbase + col;
        arow = arow < n ? arow : n - 1;

        f32x16 acc0, acc1;
        #pragma unroll
        for (int i = 0; i < 16; i++) { acc0[i] = 0.f; acc1[i] = 0.f; }

        #pragma unroll
        for (int kt = 0; kt < KT; kt++) {
            int k0 = kt * 16 + kq * 8;
            half8 af = *(const half8*)(A + (size_t)arow * K + k0);
            acc0 = __builtin_amdgcn_mfma_f32_32x32x16_f16(af, bf[0][kt], acc0, 0, 0, 0);
            acc1 = __builtin_amdgcn_mfma_f32_32x32x16_f16(af, bf[1][kt], acc1, 0, 0, 0);
        }

        #pragma unroll
        for (int r = 0; r < 16; r++) {
            int row = rbase + (r & 3) + 8 * (r >> 2) + 4 * kq;
            if (row >= n) continue;
            float rsv = rs[row];
            float v0 = fmaxf(acc0[r], 0.f);
            float v1 = fmaxf(acc1[r], 0.f);
            C16[(size_t)row * HDIM + col] = __float2half(rsv * v0);
            C16[(size_t)row * HDIM + 32 + col] = __float2half(rsv * v1);
        }
    }
}

// ---------------- MFMA fused last layer: out = relu(agg @ W1) @ Wout --------
__global__ __launch_bounds__(256) void gemm_last_mfma(const _Float16* __restrict__ A,
                                                      const float* __restrict__ W1,
                                                      const float* __restrict__ Wo,
                                                      float* __restrict__ outp, int n) {
    __shared__ __align__(16) float hb[4][32][68];   // 34.8 KB, wave-private
    int lane = (int)threadIdx.x & 63;
    int wave = (int)threadIdx.x >> 6;
    int col = lane & 31;
    int kq = lane >> 5;

    half8 b1[2][4];
    #pragma unroll
    for (int nt = 0; nt < 2; nt++) {
        #pragma unroll
        for (int kt = 0; kt < 4; kt++) {
            int c = nt * 32 + col;
            int k0 = kt * 16 + kq * 8;
            half8 b;
            #pragma unroll
            for (int i = 0; i < 8; i++)
                b[i] = (_Float16)W1[(size_t)(k0 + i) * HDIM + c];
            b1[nt][kt] = b;
        }
    }
    half8 b2[4];
    #pragma unroll
    for (int kt = 0; kt < 4; kt++) {
        int k0 = kt * 16 + kq * 8;
        half8 b;
        #pragma unroll
        for (int i = 0; i < 8; i++)
            b[i] = (_Float16)Wo[(size_t)(k0 + i) * OUTDIM + col];
        b2[kt] = b;
    }

    int ntiles = (n + 31) >> 5;
    for (int tile = blockIdx.x * 4 + wave; tile < ntiles; tile += gridDim.x * 4) {
        int rbase = tile * 32;
        int arow = rbase + col;
        arow = arow < n ? arow : n - 1;

        f32x16 acc0, acc1;
        #pragma unroll
        for (int i = 0; i < 16; i++) { acc0[i] = 0.f; acc1[i] = 0.f; }

        #pragma unroll
        for (int kt = 0; kt < 4; kt++) {
            int k0 = kt * 16 + kq * 8;
            half8 af = *(const half8*)(A + (size_t)arow * HDIM + k0);
            acc0 = __builtin_amdgcn_mfma_f32_32x32x16_f16(af, b1[0][kt], acc0, 0, 0, 0);
            acc1 = __builtin_amdgcn_mfma_f32_32x32x16_f16(af, b1[1][kt], acc1, 0, 0, 0);
        }

        #pragma unroll
        for (int r = 0; r < 16; r++) {
            int row = (r & 3) + 8 * (r >> 2) + 4 * kq;
            hb[wave][row][col] = fmaxf(acc0[r], 0.f);
            hb[wave][row][32 + col] = fmaxf(acc1[r], 0.f);
        }

        f32x16 acco;
        #pragma unroll
        for (int i = 0; i < 16; i++) acco[i] = 0.f;
        #pragma unroll
        for (int kt = 0; kt < 4; kt++) {
            int k0 = kt * 16 + kq * 8;
            float4 x0 = *(const float4*)&hb[wave][col][k0];
            float4 x1 = *(const float4*)&hb[wave][col][k0 + 4];
            half8 af2;
            af2[0] = (_Float16)x0.x; af2[1] = (_Float16)x0.y;
            af2[2] = (_Float16)x0.z; af2[3] = (_Float16)x0.w;
            af2[4] = (_Float16)x1.x; af2[5] = (_Float16)x1.y;
            af2[6] = (_Float16)x1.z; af2[7] = (_Float16)x1.w;
            acco = __builtin_amdgcn_mfma_f32_32x32x16_f16(af2, b2[kt], acco, 0, 0, 0);
        }

        #pragma unroll
        for (int r = 0; r < 16; r++) {
            int row = rbase + (r & 3) + 8 * (r >> 2) + 4 * kq;
            if (row >= n) continue;
            outp[(size_t)row * OUTDIM + col] = acco[r];
        }
    }
}

// ---------------- aggregate, 2 nodes/wave, 4-deep unroll --------------------
// PRESCALED: h16in is rs-prescaled (weights 1/0, skip*isr).
// !PRESCALED: per-edge weight rs[s]. CRITICAL (R20 lesson = R2 lesson):
// the rs shfl must be UNCONDITIONAL — all 64 lanes execute it, THEN mask.
// A shfl inside a ternary arm can lower divergently; reads from masked-off
// source lanes return 0 on CDNA -> silently dropped edges (absmax 6.6e-3).
template<bool PRESCALED>
__global__ void aggregate(const __half* __restrict__ h16in,
                          __half* __restrict__ agg16,
                          const int* __restrict__ cnt, const int* __restrict__ csr,
                          const float* __restrict__ rs, const float* __restrict__ isr,
                          int n) {
    int wave = threadIdx.x >> 6;
    int lane = threadIdx.x & 63;
    int pair = blockIdx.x * (blockDim.x >> 6) + wave;
    int node0 = pair * 2;
    if (node0 >= n) return;
    int node1 = node0 + 1;
    bool has1 = node1 < n;
    int c0 = min(cnt[node0], CAP);
    int c1 = has1 ? min(cnt[node1], CAP) : 0;
    int grp = lane >> 4;
    int gl = lane & 15;
    int sl0 = 0, sl1 = 0;
    float rsl0 = 0.f, rsl1 = 0.f;
    if (lane < c0) {
        sl0 = csr[node0 * CAP + lane];
        if (!PRESCALED) rsl0 = rs[sl0];
    }
    if (lane < c1) {
        sl1 = csr[node1 * CAP + lane];
        if (!PRESCALED) rsl1 = rs[sl1];
    }
    float4 a0 = make_float4(0.f, 0.f, 0.f, 0.f);
    float4 a1 = make_float4(0.f, 0.f, 0.f, 0.f);
    int t0m = c0 - 1, t1m = c1 - 1;
    int trips = max((c0 + 3) >> 2, (c1 + 3) >> 2);
    int j = 0;
    for (; j + 4 <= trips; j += 4) {
        #pragma unroll
        for (int u = 0; u < 4; u++) {
            int t = 4 * (j + u) + grp;
            bool v0 = t < c0, v1 = t < c1;
            int u0 = max(min(t, t0m), 0);
            int u1 = max(min(t, t1m), 0);
            int s0 = __shfl(sl0, u0);                   // unconditional
            int s1 = __shfl(sl1, u1);
            float rw0 = PRESCALED ? 1.f : __shfl(rsl0, u0);  // unconditional
            float rw1 = PRESCALED ? 1.f : __shfl(rsl1, u1);
            float w0 = v0 ? rw0 : 0.f;                  // mask AFTER shfl
            float w1 = v1 ? rw1 : 0.f;
            uint2 q0 = ((const uint2*)(h16in + (size_t)s0 * HDIM))[gl];
            uint2 q1 = ((const uint2*)(h16in + (size_t)s1 * HDIM))[gl];
            float2 fa = h2f(q0.x), fb = h2f(q0.y);
            a0.x += w0 * fa.x; a0.y += w0 * fa.y;
            a0.z += w0 * fb.x; a0.w += w0 * fb.y;
            fa = h2f(q1.x); fb = h2f(q1.y);
            a1.x += w1 * fa.x; a1.y += w1 * fa.y;
            a1.z += w1 * fb.x; a1.w += w1 * fb.y;
        }
    }
    for (; j < trips; j++) {
        int t = 4 * j + grp;
        bool v0 = t < c0, v1 = t < c1;
        int u0 = max(min(t, t0m), 0);
        int u1 = max(min(t, t1m), 0);
        int s0 = __shfl(sl0, u0);
        int s1 = __shfl(sl1, u1);
        float rw0 = PRESCALED ? 1.f : __shfl(rsl0, u0);
        float rw1 = PRESCALED ? 1.f : __shfl(rsl1, u1);
        float w0 = v0 ? rw0 : 0.f;
        float w1 = v1 ? rw1 : 0.f;
        uint2 q0 = ((const uint2*)(h16in + (size_t)s0 * HDIM))[gl];
        uint2 q1 = ((const uint2*)(h16in + (size_t)s1 * HDIM))[gl];
        float2 fa = h2f(q0.x), fb = h2f(q0.y);
        a0.x += w0 * fa.x; a0.y += w0 * fa.y;
        a0.z += w0 * fb.x; a0.w += w0 * fb.y;
        fa = h2f(q1.x); fb = h2f(q1.y);
        a1.x += w1 * fa.x; a1.y += w1 * fa.y;
        a1.z += w1 * fb.x; a1.w += w1 * fb.y;
    }
    #pragma unroll
    for (int m = 16; m < 64; m <<= 1) {
        a0.x += __shfl_xor(a0.x, m);
        a0.y += __shfl_xor(a0.y, m);
        a0.z += __shfl_xor(a0.z, m);
        a0.w += __shfl_xor(a0.w, m);
        a1.x += __shfl_xor(a1.x, m);
        a1.y += __shfl_xor(a1.y, m);
        a1.z += __shfl_xor(a1.z, m);
        a1.w += __shfl_xor(a1.w, m);
    }
    int node = -1;
    float4 acc;
    if (grp == 0) { node = node0; acc = a0; }
    else if (grp == 1 && has1) { node = node1; acc = a1; }
    if (node >= 0) {
        float rsd = rs[node];
        uint2 sk2 = ((const uint2*)(h16in + (size_t)node * HDIM))[gl];
        float2 ska = h2f(sk2.x), skb = h2f(sk2.y);
        float skscale = PRESCALED ? isr[node] : 1.0f;
        acc.x = acc.x * rsd + ska.x * skscale;
        acc.y = acc.y * rsd + ska.y * skscale;
        acc.z = acc.z * rsd + skb.x * skscale;
        acc.w = acc.w * rsd + skb.y * skscale;
        __half2 q0 = __floats2half2_rn(acc.x, acc.y);
        __half2 q1 = __floats2half2_rn(acc.z, acc.w);
        uint2 st;
        st.x = *(unsigned int*)&q0;
        st.y = *(unsigned int*)&q1;
        ((uint2*)(agg16 + (size_t)node * HDIM))[gl] = st;
    }
}

extern "C" void kernel_launch(void* const* d_in, const int* in_sizes, int n_in,
                              void* d_out, int out_size, void* d_ws, size_t ws_size,
                              hipStream_t stream) {
    const float* x    = (const float*)d_in[0];
    const int*   ei   = (const int*)d_in[1];
    const float* Win  = (const float*)d_in[2];
    const float* Wl   = (const float*)d_in[3];
    const float* Wout = (const float*)d_in[4];
    float* out = (float*)d_out;

    int n = in_sizes[0] / INDIM;   // 100000
    int e = in_sizes[1] / 2;       // 1600000
    const int* dst = ei;           // edge_index[0]
    const int* src = ei + e;       // edge_index[1]

    int nb = (n + BNODES - 1) / BNODES;   // 782 buckets

    // workspace: gcur | cnt | rs | isr | binned | csr | h16a | agg16a | h16b | agg16b
    char* w = (char*)d_ws;
    int* gcur = (int*)w;       w += 1024 * 4;
    int* cnt = (int*)w;        w += (size_t)n * 4;
    float* rs = (float*)w;     w += (size_t)n * 4;
    float* isr = (float*)w;    w += (size_t)n * 4;
    w = (char*)(((uintptr_t)w + 255) & ~(uintptr_t)255);
    int* binned = (int*)w;     w += (size_t)nb * BCAP * 4;          // 7.2 MB
    int* csr = (int*)w;        w += (size_t)nb * BNODES * CAP * 4;  // 25.6 MB
    __half* h16a = (__half*)w;   w += (size_t)n * HDIM * 2;         // 12.8 MB
    __half* agg16a = (__half*)w; w += (size_t)n * HDIM * 2;         // 12.8 MB
    __half* h16b = (__half*)w;   w += (size_t)n * HDIM * 2;         // 12.8 MB
    __half* agg16b = (__half*)w; w += (size_t)n * HDIM * 2;         // 12.8 MB

    hipMemsetAsync(gcur, 0, 1024 * 4, stream);

    int ablocks = (e + EPB - 1) / EPB;     // 391
    int ntiles = (n + 31) / 32;            // 3125
    int gmfma = (ntiles + 3) / 4;          // 782
    int gagg = (n + 7) / 8;                // 2 nodes/wave, 4 waves/block

    // K1: bin_edges ∥ gemm_in (unscaled h16a) — independent workloads
    bin_and_gemm_in<<<ablocks + gmfma, 256, 0, stream>>>(
        dst, src, gcur, binned, e, nb, ablocks, x, Win, h16a, n);

    // K2: build padded CSR + rs/isr
    build_csr<<<nb, 256, 0, stream>>>(gcur, binned, cnt, rs, isr, csr, n);

    // layer 0: per-edge rs (h16a unscaled)
    aggregate<false><<<gagg, 256, 0, stream>>>(h16a, agg16a, cnt, csr, rs, isr, n);
    gemm_mid<<<gmfma, 256, 0, stream>>>((const _Float16*)agg16a, Wl, h16b, rs, n);

    // layer 1 + output (h16b prescaled)
    aggregate<true><<<gagg, 256, 0, stream>>>(h16b, agg16b, cnt, csr, rs, isr, n);
    gemm_last_mfma<<<gmfma, 256, 0, stream>>>((const _Float16*)agg16b,
                                              Wl + (size_t)HDIM * HDIM,
                                              Wout, out, n);
}

// Round 24
// 145.124 us; speedup vs baseline: 1.0106x; 1.0106x over previous
//
#include <hip/hip_runtime.h>
#include <hip/hip_fp16.h>

#define HDIM 64
#define INDIM 128
#define OUTDIM 32
#define CAP 64        // padded-CSR capacity per node; deg ~ Poisson(16)
#define BNODES 128    // nodes per bucket (bucket = dst >> 7)
#define EPB 4096      // edges per block in pass A
#define BCAP 2304     // per-bucket edge capacity (mean 2046, +5.7 sigma)
#define SRCBITS 17    // src ids < 2^17 (n <= 131072)

typedef __attribute__((ext_vector_type(8))) _Float16 half8;
typedef __attribute__((ext_vector_type(16))) float f32x16;

__device__ __forceinline__ float2 h2f(unsigned int u) {
    return __half22float2(*(__half2*)&u);
}

// ---------------- pass A: bin edges by dst-bucket ----------------
__global__ __launch_bounds__(256) void bin_edges(const int* __restrict__ dst,
                                                 const int* __restrict__ src,
                                                 int* __restrict__ gcur,
                                                 int* __restrict__ binned,
                                                 int e, int nb) {
    __shared__ int hist[1024];
    __shared__ int base[1024];
    for (int i = threadIdx.x; i < nb; i += 256) hist[i] = 0;
    __syncthreads();

    int e0 = blockIdx.x * EPB + (int)threadIdx.x * 16;
    int d[16], s[16], p[16];
    bool vec_ok = ((e & 3) == 0);
    #pragma unroll
    for (int k = 0; k < 4; k++) {
        int i = e0 + 4 * k;
        if (vec_ok && i + 4 <= e) {
            int4 d4 = *(const int4*)(dst + i);
            int4 s4 = *(const int4*)(src + i);
            d[4*k+0] = d4.x; d[4*k+1] = d4.y; d[4*k+2] = d4.z; d[4*k+3] = d4.w;
            s[4*k+0] = s4.x; s[4*k+1] = s4.y; s[4*k+2] = s4.z; s[4*k+3] = s4.w;
        } else {
            #pragma unroll
            for (int j = 0; j < 4; j++) {
                int ii = i + j;
                if (ii < e) { d[4*k+j] = dst[ii]; s[4*k+j] = src[ii]; }
                else        { d[4*k+j] = -1;      s[4*k+j] = 0; }
            }
        }
    }
    #pragma unroll
    for (int k = 0; k < 16; k++)
        if (d[k] >= 0) p[k] = atomicAdd(&hist[d[k] >> 7], 1);
    __syncthreads();
    for (int b = threadIdx.x; b < nb; b += 256) {
        int h = hist[b];
        base[b] = h ? atomicAdd(&gcur[b], h) : 0;
    }
    __syncthreads();
    #pragma unroll
    for (int k = 0; k < 16; k++) {
        if (d[k] < 0) continue;
        int b = d[k] >> 7;
        int pos = base[b] + p[k];
        if (pos < BCAP)
            binned[(size_t)b * BCAP + pos] = ((d[k] & (BNODES - 1)) << SRCBITS) | s[k];
    }
}

// ---------------- pass B: per-bucket padded CSR built in LDS ----------------
__global__ __launch_bounds__(256) void build_csr(const int* __restrict__ gcur,
                                                 const int* __restrict__ binned,
                                                 int* __restrict__ cnt,
                                                 float* __restrict__ rs,
                                                 float* __restrict__ isr,
                                                 int* __restrict__ csr, int n) {
    __shared__ int lcsr[BNODES * CAP];   // 32 KiB
    __shared__ int lcnt[BNODES];
    if (threadIdx.x < BNODES) lcnt[threadIdx.x] = 0;
    __syncthreads();
    int b = blockIdx.x;
    int m = min(gcur[b], BCAP);
    const int* be = binned + (size_t)b * BCAP;
    for (int i = threadIdx.x; i < m; i += 256) {
        int v = be[i];
        int ld = v >> SRCBITS;
        int pos = atomicAdd(&lcnt[ld], 1);
        if (pos < CAP) lcsr[ld * CAP + pos] = v & ((1 << SRCBITS) - 1);
    }
    __syncthreads();
    int4* gout = (int4*)(csr + (size_t)b * (BNODES * CAP));
    const int4* lin = (const int4*)lcsr;
    #pragma unroll 2
    for (int i = threadIdx.x; i < BNODES * CAP / 4; i += 256) gout[i] = lin[i];
    int node = b * BNODES + (int)threadIdx.x;
    if (threadIdx.x < BNODES && node < n) {
        int c = lcnt[threadIdx.x];
        cnt[node] = c;
        float cf = (float)c + 1.0f;
        rs[node] = rsqrtf(cf);
        isr[node] = sqrtf(cf);   // 1/rs: recovers unscaled h from the shadow
    }
}

// ---------------- MFMA node GEMM: C16 = fp16(rs * op(A @ W)) ----------------
// v_mfma_f32_32x32x16_f16, wave = 32 rows x 64 cols; W fragments in registers.
// Layouts: A row=l&31, k=8*(l>>5)+i; B col=l&31, same k;
// C/D col=lane&31, row=(reg&3)+8*(reg>>2)+4*(lane>>5)  [HW-verified m74/m101].
template<int K, bool A16, bool RELU>
__global__ __launch_bounds__(256) void gemm_mfma(const void* __restrict__ Av,
                                                 const float* __restrict__ W,
                                                 __half* __restrict__ C16,
                                                 const float* __restrict__ rs,
                                                 int n) {
    constexpr int KT = K / 16;
    int lane = (int)threadIdx.x & 63;
    int wave = (int)threadIdx.x >> 6;
    int col = lane & 31;
    int kq = lane >> 5;           // which k-half of the fragment this lane holds

    half8 bf[2][KT];
    #pragma unroll
    for (int nt = 0; nt < 2; nt++) {
        #pragma unroll
        for (int kt = 0; kt < KT; kt++) {
            int c = nt * 32 + col;
            int k0 = kt * 16 + kq * 8;
            half8 b;
            #pragma unroll
            for (int i = 0; i < 8; i++)
                b[i] = (_Float16)W[(size_t)(k0 + i) * HDIM + c];
            bf[nt][kt] = b;
        }
    }

    int ntiles = (n + 31) >> 5;
    for (int tile = blockIdx.x * 4 + wave; tile < ntiles; tile += gridDim.x * 4) {
        int rbase = tile * 32;
        int arow = rbase + col;
        arow = arow < n ? arow : n - 1;     // clamp

        f32x16 acc0, acc1;
        #pragma unroll
        for (int i = 0; i < 16; i++) { acc0[i] = 0.f; acc1[i] = 0.f; }

        #pragma unroll
        for (int kt = 0; kt < KT; kt++) {
            int k0 = kt * 16 + kq * 8;
            half8 af;
            if (A16) {
                af = *(const half8*)((const _Float16*)Av + (size_t)arow * K + k0);
            } else {
                const float* ap = (const float*)Av + (size_t)arow * K + k0;
                float4 x0 = *(const float4*)ap;
                float4 x1 = *(const float4*)(ap + 4);
                af[0] = (_Float16)x0.x; af[1] = (_Float16)x0.y;
                af[2] = (_Float16)x0.z; af[3] = (_Float16)x0.w;
                af[4] = (_Float16)x1.x; af[5] = (_Float16)x1.y;
                af[6] = (_Float16)x1.z; af[7] = (_Float16)x1.w;
            }
            acc0 = __builtin_amdgcn_mfma_f32_32x32x16_f16(af, bf[0][kt], acc0, 0, 0, 0);
            acc1 = __builtin_amdgcn_mfma_f32_32x32x16_f16(af, bf[1][kt], acc1, 0, 0, 0);
        }

        #pragma unroll
        for (int r = 0; r < 16; r++) {
            int row = rbase + (r & 3) + 8 * (r >> 2) + 4 * kq;
            if (row >= n) continue;
            float rsv = rs[row];
            float v0 = acc0[r], v1 = acc1[r];
            if (RELU) { v0 = fmaxf(v0, 0.f); v1 = fmaxf(v1, 0.f); }
            C16[(size_t)row * HDIM + col] = __float2half(rsv * v0);
            C16[(size_t)row * HDIM + 32 + col] = __float2half(rsv * v1);
        }
    }
}

// ---------------- MFMA fused last layer: out = relu(agg @ W1) @ Wout --------
// Per wave: 32-row tile; H via 8 MFMAs -> wave-private LDS slice; re-read as
// fp16 A-frags (same-wave DS ordering, no barrier); out via 4 MFMAs.
__global__ __launch_bounds__(256) void gemm_last_mfma(const _Float16* __restrict__ A,
                                                      const float* __restrict__ W1,
                                                      const float* __restrict__ Wo,
                                                      float* __restrict__ outp, int n) {
    __shared__ __align__(16) float hb[4][32][68];   // 34.8 KB, wave-private
    int lane = (int)threadIdx.x & 63;
    int wave = (int)threadIdx.x >> 6;
    int col = lane & 31;
    int kq = lane >> 5;

    half8 b1[2][4];
    #pragma unroll
    for (int nt = 0; nt < 2; nt++) {
        #pragma unroll
        for (int kt = 0; kt < 4; kt++) {
            int c = nt * 32 + col;
            int k0 = kt * 16 + kq * 8;
            half8 b;
            #pragma unroll
            for (int i = 0; i < 8; i++)
                b[i] = (_Float16)W1[(size_t)(k0 + i) * HDIM + c];
            b1[nt][kt] = b;
        }
    }
    half8 b2[4];
    #pragma unroll
    for (int kt = 0; kt < 4; kt++) {
        int k0 = kt * 16 + kq * 8;
        half8 b;
        #pragma unroll
        for (int i = 0; i < 8; i++)
            b[i] = (_Float16)Wo[(size_t)(k0 + i) * OUTDIM + col];
        b2[kt] = b;
    }

    int ntiles = (n + 31) >> 5;
    for (int tile = blockIdx.x * 4 + wave; tile < ntiles; tile += gridDim.x * 4) {
        int rbase = tile * 32;
        int arow = rbase + col;
        arow = arow < n ? arow : n - 1;

        f32x16 acc0, acc1;
        #pragma unroll
        for (int i = 0; i < 16; i++) { acc0[i] = 0.f; acc1[i] = 0.f; }

        #pragma unroll
        for (int kt = 0; kt < 4; kt++) {
            int k0 = kt * 16 + kq * 8;
            half8 af = *(const half8*)(A + (size_t)arow * HDIM + k0);
            acc0 = __builtin_amdgcn_mfma_f32_32x32x16_f16(af, b1[0][kt], acc0, 0, 0, 0);
            acc1 = __builtin_amdgcn_mfma_f32_32x32x16_f16(af, b1[1][kt], acc1, 0, 0, 0);
        }

        #pragma unroll
        for (int r = 0; r < 16; r++) {
            int row = (r & 3) + 8 * (r >> 2) + 4 * kq;
            hb[wave][row][col] = fmaxf(acc0[r], 0.f);
            hb[wave][row][32 + col] = fmaxf(acc1[r], 0.f);
        }

        f32x16 acco;
        #pragma unroll
        for (int i = 0; i < 16; i++) acco[i] = 0.f;
        #pragma unroll
        for (int kt = 0; kt < 4; kt++) {
            int k0 = kt * 16 + kq * 8;
            float4 x0 = *(const float4*)&hb[wave][col][k0];
            float4 x1 = *(const float4*)&hb[wave][col][k0 + 4];
            half8 af2;
            af2[0] = (_Float16)x0.x; af2[1] = (_Float16)x0.y;
            af2[2] = (_Float16)x0.z; af2[3] = (_Float16)x0.w;
            af2[4] = (_Float16)x1.x; af2[5] = (_Float16)x1.y;
            af2[6] = (_Float16)x1.z; af2[7] = (_Float16)x1.w;
            acco = __builtin_amdgcn_mfma_f32_32x32x16_f16(af2, b2[kt], acco, 0, 0, 0);
        }

        #pragma unroll
        for (int r = 0; r < 16; r++) {
            int row = rbase + (r & 3) + 8 * (r >> 2) + 4 * kq;
            if (row >= n) continue;
            outp[(size_t)row * OUTDIM + col] = acco[r];
        }
    }
}

// ---------------- aggregate: 2 nodes/wave, 4-deep unroll (prescaled) -------
// agg16 = fp16(rs[d]*sum h16[s] + isr[d]*h16[d]); h16 is rs-prescaled.
// 8 row-gathers in flight per wave. All shfls unconditional (R2/R20 lesson).
__global__ void aggregate(const __half* __restrict__ h16in,
                          __half* __restrict__ agg16,
                          const int* __restrict__ cnt, const int* __restrict__ csr,
                          const float* __restrict__ rs, const float* __restrict__ isr,
                          int n) {
    int wave = threadIdx.x >> 6;
    int lane = threadIdx.x & 63;
    int pair = blockIdx.x * (blockDim.x >> 6) + wave;
    int node0 = pair * 2;
    if (node0 >= n) return;
    int node1 = node0 + 1;
    bool has1 = node1 < n;
    int c0 = min(cnt[node0], CAP);
    int c1 = has1 ? min(cnt[node1], CAP) : 0;
    int grp = lane >> 4;
    int gl = lane & 15;
    int sl0 = 0, sl1 = 0;
    if (lane < c0) sl0 = csr[node0 * CAP + lane];
    if (lane < c1) sl1 = csr[node1 * CAP + lane];
    float4 a0 = make_float4(0.f, 0.f, 0.f, 0.f);
    float4 a1 = make_float4(0.f, 0.f, 0.f, 0.f);
    int t0m = c0 - 1, t1m = c1 - 1;
    int trips = max((c0 + 3) >> 2, (c1 + 3) >> 2);
    int j = 0;
    for (; j + 4 <= trips; j += 4) {
        #pragma unroll
        for (int u = 0; u < 4; u++) {
            int t = 4 * (j + u) + grp;
            float w0 = (t < c0) ? 1.f : 0.f;
            float w1 = (t < c1) ? 1.f : 0.f;
            int u0 = max(min(t, t0m), 0);
            int u1 = max(min(t, t1m), 0);
            int s0 = __shfl(sl0, u0);
            int s1 = __shfl(sl1, u1);
            uint2 q0 = ((const uint2*)(h16in + (size_t)s0 * HDIM))[gl];
            uint2 q1 = ((const uint2*)(h16in + (size_t)s1 * HDIM))[gl];
            float2 fa = h2f(q0.x), fb = h2f(q0.y);
            a0.x += w0 * fa.x; a0.y += w0 * fa.y;
            a0.z += w0 * fb.x; a0.w += w0 * fb.y;
            fa = h2f(q1.x); fb = h2f(q1.y);
            a1.x += w1 * fa.x; a1.y += w1 * fa.y;
            a1.z += w1 * fb.x; a1.w += w1 * fb.y;
        }
    }
    for (; j < trips; j++) {
        int t = 4 * j + grp;
        float w0 = (t < c0) ? 1.f : 0.f;
        float w1 = (t < c1) ? 1.f : 0.f;
        int u0 = max(min(t, t0m), 0);
        int u1 = max(min(t, t1m), 0);
        int s0 = __shfl(sl0, u0);
        int s1 = __shfl(sl1, u1);
        uint2 q0 = ((const uint2*)(h16in + (size_t)s0 * HDIM))[gl];
        uint2 q1 = ((const uint2*)(h16in + (size_t)s1 * HDIM))[gl];
        float2 fa = h2f(q0.x), fb = h2f(q0.y);
        a0.x += w0 * fa.x; a0.y += w0 * fa.y;
        a0.z += w0 * fb.x; a0.w += w0 * fb.y;
        fa = h2f(q1.x); fb = h2f(q1.y);
        a1.x += w1 * fa.x; a1.y += w1 * fa.y;
        a1.z += w1 * fb.x; a1.w += w1 * fb.y;
    }
    #pragma unroll
    for (int m = 16; m < 64; m <<= 1) {
        a0.x += __shfl_xor(a0.x, m);
        a0.y += __shfl_xor(a0.y, m);
        a0.z += __shfl_xor(a0.z, m);
        a0.w += __shfl_xor(a0.w, m);
        a1.x += __shfl_xor(a1.x, m);
        a1.y += __shfl_xor(a1.y, m);
        a1.z += __shfl_xor(a1.z, m);
        a1.w += __shfl_xor(a1.w, m);
    }
    int node = -1;
    float4 acc;
    if (grp == 0) { node = node0; acc = a0; }
    else if (grp == 1 && has1) { node = node1; acc = a1; }
    if (node >= 0) {
        float rsd = rs[node];
        float isrd = isr[node];
        uint2 sk2 = ((const uint2*)(h16in + (size_t)node * HDIM))[gl];
        float2 ska = h2f(sk2.x), skb = h2f(sk2.y);
        acc.x = acc.x * rsd + ska.x * isrd;
        acc.y = acc.y * rsd + ska.y * isrd;
        acc.z = acc.z * rsd + skb.x * isrd;
        acc.w = acc.w * rsd + skb.y * isrd;
        __half2 q0 = __floats2half2_rn(acc.x, acc.y);
        __half2 q1 = __floats2half2_rn(acc.z, acc.w);
        uint2 st;
        st.x = *(unsigned int*)&q0;
        st.y = *(unsigned int*)&q1;
        ((uint2*)(agg16 + (size_t)node * HDIM))[gl] = st;
    }
}

extern "C" void kernel_launch(void* const* d_in, const int* in_sizes, int n_in,
                              void* d_out, int out_size, void* d_ws, size_t ws_size,
                              hipStream_t stream) {
    const float* x    = (const float*)d_in[0];
    const int*   ei   = (const int*)d_in[1];
    const float* Win  = (const float*)d_in[2];
    const float* Wl   = (const float*)d_in[3];
    const float* Wout = (const float*)d_in[4];
    float* out = (float*)d_out;

    int n = in_sizes[0] / INDIM;   // 100000
    int e = in_sizes[1] / 2;       // 1600000
    const int* dst = ei;           // edge_index[0]
    const int* src = ei + e;       // edge_index[1]

    int nb = (n + BNODES - 1) / BNODES;   // 782 buckets

    // workspace: gcur | cnt | rs | isr | binned | csr | h16a | agg16a | h16b | agg16b
    char* w = (char*)d_ws;
    int* gcur = (int*)w;       w += 1024 * 4;
    int* cnt = (int*)w;        w += (size_t)n * 4;
    float* rs = (float*)w;     w += (size_t)n * 4;
    float* isr = (float*)w;    w += (size_t)n * 4;
    w = (char*)(((uintptr_t)w + 255) & ~(uintptr_t)255);
    int* binned = (int*)w;     w += (size_t)nb * BCAP * 4;          // 7.2 MB
    int* csr = (int*)w;        w += (size_t)nb * BNODES * CAP * 4;  // 25.6 MB
    __half* h16a = (__half*)w;   w += (size_t)n * HDIM * 2;         // 12.8 MB
    __half* agg16a = (__half*)w; w += (size_t)n * HDIM * 2;         // 12.8 MB
    __half* h16b = (__half*)w;   w += (size_t)n * HDIM * 2;         // 12.8 MB
    __half* agg16b = (__half*)w; w += (size_t)n * HDIM * 2;         // 12.8 MB

    hipMemsetAsync(gcur, 0, 1024 * 4, stream);

    // two-phase padded-CSR build
    int ablocks = (e + EPB - 1) / EPB;    // 391
    bin_edges<<<ablocks, 256, 0, stream>>>(dst, src, gcur, binned, e, nb);
    build_csr<<<nb, 256, 0, stream>>>(gcur, binned, cnt, rs, isr, csr, n);

    int ntiles = (n + 31) / 32;            // 3125
    int gmfma = (ntiles + 3) / 4;          // 782 blocks (4 waves each)
    int gagg = (n + 7) / 8;                // 2 nodes/wave, 4 waves/block

    // h16a = fp16(rs * (x @ W_in))   [MFMA]
    gemm_mfma<INDIM, false, false><<<gmfma, 256, 0, stream>>>(x, Win, h16a, rs, n);

    // layer 0
    aggregate<<<gagg, 256, 0, stream>>>(h16a, agg16a, cnt, csr, rs, isr, n);
    gemm_mfma<HDIM, true, true><<<gmfma, 256, 0, stream>>>(agg16a, Wl, h16b, rs, n);

    // layer 1 + output  [MFMA, fused via wave-private LDS transpose]
    aggregate<<<gagg, 256, 0, stream>>>(h16b, agg16b, cnt, csr, rs, isr, n);
    gemm_last_mfma<<<gmfma, 256, 0, stream>>>((const _Float16*)agg16b,
                                              Wl + (size_t)HDIM * HDIM,
                                              Wout, out, n);
}